// Round 12
// baseline (10387.696 us; speedup 1.0000x reference)
//
#include <hip/hip_runtime.h>
#include <math.h>

#define BDIM 512
#define BR   64
#define D    128
#define SPD  130      // state LDS row stride (doubles); 1040B rows -> b128-aligned
#define SWOP 12       // sWo row stride (floats)
#define TT   32
#define NB   8
#define NL   3

__device__ __forceinline__ double c19_act_d(double x) {
    const double PI_D = 3.14159265358979323846;
    const double L6   = 6.0 * PI_D;
    double scaled = x * (1.0 / PI_D);
    double n = floor(scaled);
    double t = scaled - n;
    double h = t * (1.0 - t);
    double halfn = n * 0.5;
    double fr = halfn - floor(halfn);   // 0.0 (even n) or 0.5 (odd n)
    double sgn = (fr < 0.25) ? 1.0 : -1.0;
    double core = PI_D * (sgn * h + 4.0 * h * h);
    double r = core;
    r = (x <= -L6) ? (x + L6) : r;
    r = (x >=  L6) ? (x - L6) : r;
    return r;
}

// Stage 64 KB W tile into LDS via async global->LDS (no VGPR round-trip).
// 8 waves x 8 instrs x 1KB = 64KB, linear row-major.
__device__ __forceinline__ void stage_W_async(const float* __restrict__ wsrc,
                                              float* sW, int tid) {
    const int wv   = tid >> 6;    // wave 0..7
    const int lane = tid & 63;
    #pragma unroll
    for (int it = 0; it < 8; ++it) {
        int base = it * 2048 + wv * 256;            // floats
        const float* g = wsrc + base + lane * 4;
        float* l = sW + base;                        // wave-uniform LDS base
        __builtin_amdgcn_global_load_lds(
            (const __attribute__((address_space(1))) void*)g,
            (__attribute__((address_space(3))) void*)l,
            16, 0, 0);
    }
}

__global__ __launch_bounds__(BDIM, 1) void miniphi_kernel(
    const float* __restrict__ x,  const float* __restrict__ Wi, const float* __restrict__ bi,
    const float* __restrict__ Wo, const float* __restrict__ bo,
    const float* __restrict__ g_state, const float* __restrict__ b_state,
    const float* __restrict__ Ws, const float* __restrict__ bs,
    const float* __restrict__ gs, const float* __restrict__ betas,
    float* __restrict__ out)
{
    __shared__ double sStateD[BR][SPD];    // 66560 B; rows FULLY wave-private (wave w: rows 8w..8w+7)
    __shared__ float  sW[D * D];           // 65536 B; the ONLY cross-wave object in the t-loop
    __shared__ float  sWi[NB][D];
    __shared__ float  sWo[D][SWOP];
    __shared__ float  sBi[D], sGst[D], sBst[D];
    __shared__ double sGsD[NL][D];         // g (f64, exact)
    __shared__ double sGW[NL][D];          // (g @ W)[c]
    __shared__ double sBWbs[NL][D];        // (beta @ W)[c] + bs[c]
    __shared__ float  sBo[NB];             // total ~149.5 KB -> 1 block/CU, 8 waves (2/SIMD)

    const int tid = threadIdx.x;

    for (int i = tid; i < NB * D; i += BDIM) sWi[i >> 7][i & 127] = Wi[i];
    for (int i = tid; i < D * NB; i += BDIM) sWo[i >> 3][i & 7] = Wo[i];
    for (int i = tid; i < D; i += BDIM) { sBi[i] = bi[i]; sGst[i] = g_state[i]; sBst[i] = b_state[i]; }
    for (int i = tid; i < NL * D; i += BDIM) sGsD[i >> 7][i & 127] = (double)gs[i];
    if (tid < NB) sBo[tid] = bo[tid];
    for (int i = tid; i < BR * D; i += BDIM) sStateD[i >> 7][i & 127] = 0.0;
    // LN-fold per-layer column vectors (f64)
    if (tid < NL * D) {
        int l = tid >> 7, c = tid & 127;
        const float* wl = Ws + (size_t)l * D * D;
        double gw = 0.0, bw = 0.0;
        for (int k = 0; k < D; ++k) {
            double w = (double)wl[k * D + c];
            gw = fma((double)gs[l * D + k], w, gw);
            bw = fma((double)betas[l * D + k], w, bw);
        }
        sGW[l][c] = gw;
        sBWbs[l][c] = bw + (double)bs[l * D + c];
    }
    __syncthreads();

    const int rLN = tid >> 3;        // 0..63 : LN row (8 lanes/row; wave w owns rows 8w..8w+7)
    const int sL  = tid & 7;         // 0..7  : lane owns cols {sL + 8*j, j=0..15} in LN phases
    const int wv  = tid >> 6;        // wave 0..7
    const int l   = tid & 63;        // GEMM cols {l, l+64}
    const int r0  = wv * 8;          // GEMM rows r0..r0+7 (== LN rows of this wave)
    const size_t rowg = (size_t)blockIdx.x * BR;

    for (int t = 0; t < TT; ++t) {
        __syncthreads();             // BAR-A0: prev t's layer-2 GEMM done reading sW
        stage_W_async(Ws, sW, tid);  // async L0 stage, hides under step 1

        // ---------- step 1 (wave-private rows, no barrier) ----------
        {
            const float* xp = x + (rowg + (size_t)rLN) * (TT * NB) + (size_t)t * NB;
            float4 xa = *(const float4*)(xp);
            float4 xb = *(const float4*)(xp + 4);
            double xv[8] = {(double)xa.x, (double)xa.y, (double)xa.z, (double)xa.w,
                            (double)xb.x, (double)xb.y, (double)xb.z, (double)xb.w};

            double v[16];
            #pragma unroll
            for (int j = 0; j < 16; ++j) v[j] = sStateD[rLN][sL + 8 * j];

            double sum = 0.0;
            #pragma unroll
            for (int j = 0; j < 16; ++j) sum += v[j];
            sum += __shfl_xor(sum, 1); sum += __shfl_xor(sum, 2); sum += __shfl_xor(sum, 4);
            double mu = sum * (1.0 / 128.0);
            double sq = 0.0;
            #pragma unroll
            for (int j = 0; j < 16; ++j) { double dd = v[j] - mu; sq += dd * dd; }
            sq += __shfl_xor(sq, 1); sq += __shfl_xor(sq, 2); sq += __shfl_xor(sq, 4);
            double rstd = 1.0 / sqrt(sq * (1.0 / 128.0) + 1e-5);

            #pragma unroll
            for (int j = 0; j < 16; ++j) {
                int c = sL + 8 * j;
                double inp = (double)sBi[c];
                #pragma unroll
                for (int k = 0; k < 8; ++k)
                    inp = fma(xv[k], (double)sWi[k][c], inp);
                double ln = (v[j] - mu) * rstd * (double)sGst[c] + (double)sBst[c];
                sStateD[rLN][c] = 0.618 * ln + 0.382 * inp;
            }
        }

        // ---------- step 2: 3 residual layers ----------
        for (int layer = 0; layer < NL; ++layer) {
            // LN reductions (wave-private) -> per-row rstd/mu2 in REGISTERS
            double rstdv[8], mu2v[8];
            {
                double v[16];
                #pragma unroll
                for (int j = 0; j < 16; ++j) v[j] = sStateD[rLN][sL + 8 * j];
                double sum = 0.0;
                #pragma unroll
                for (int j = 0; j < 16; ++j) sum += v[j];
                sum += __shfl_xor(sum, 1); sum += __shfl_xor(sum, 2); sum += __shfl_xor(sum, 4);
                double mu = sum * (1.0 / 128.0);
                double sq = 0.0;
                #pragma unroll
                for (int j = 0; j < 16; ++j) { double dd = v[j] - mu; sq += dd * dd; }
                sq += __shfl_xor(sq, 1); sq += __shfl_xor(sq, 2); sq += __shfl_xor(sq, 4);
                double rstd = 1.0 / sqrt(sq * (1.0 / 128.0) + 1e-5);
                double mu2  = mu * rstd;
                // broadcast row-values across the wave (group r sits at lanes 8r..8r+7)
                #pragma unroll
                for (int r = 0; r < 8; ++r) {
                    rstdv[r] = __shfl(rstd, r * 8);
                    mu2v[r]  = __shfl(mu2,  r * 8);
                }
            }
            __syncthreads();   // BAR-B: sW staged (implicit vmcnt(0) drain)

            // GEMM: 8 rows x 2 cols per thread; A = wave-uniform b128 broadcasts
            double acc[8][2];
            #pragma unroll
            for (int r = 0; r < 8; ++r) { acc[r][0] = 0.0; acc[r][1] = 0.0; }

            const double* gvec = sGsD[layer];
            #pragma unroll 8
            for (int k0 = 0; k0 < D; k0 += 2) {
                double2 gv = *(const double2*)&gvec[k0];
                float w00 = sW[k0 * D + l],       w01 = sW[k0 * D + l + 64];
                float w10 = sW[(k0 + 1) * D + l], w11 = sW[(k0 + 1) * D + l + 64];
                double b00 = gv.x * (double)w00, b01 = gv.x * (double)w01;
                double b10 = gv.y * (double)w10, b11 = gv.y * (double)w11;
                #pragma unroll
                for (int r = 0; r < 8; ++r) {
                    double2 a = *(const double2*)&sStateD[r0 + r][k0];
                    acc[r][0] = fma(a.y, b10, fma(a.x, b00, acc[r][0]));
                    acc[r][1] = fma(a.y, b11, fma(a.x, b01, acc[r][1]));
                }
            }

            // epilogue: wave-local state RMW, NO barriers
            {
                double gwc0 = sGW[layer][l],    gwc1 = sGW[layer][l + 64];
                double bwc0 = sBWbs[layer][l],  bwc1 = sBWbs[layer][l + 64];
                #pragma unroll
                for (int r = 0; r < 8; ++r) {
                    double y0 = fma(rstdv[r], acc[r][0], fma(-mu2v[r], gwc0, bwc0));
                    double y1 = fma(rstdv[r], acc[r][1], fma(-mu2v[r], gwc1, bwc1));
                    sStateD[r0 + r][l]      += c19_act_d(y0);
                    sStateD[r0 + r][l + 64] += c19_act_d(y1);
                }
            }

            if (layer + 1 < NL) {
                __syncthreads();   // BAR-A(next): all waves done reading sW
                stage_W_async(Ws + (size_t)(layer + 1) * D * D, sW, tid);
                // next iteration's LN overlaps the async load
            }
        }

        // ---------- step 3: out = state @ Wo + bo (wave-private rows, no barrier) ----------
        {
            double accj[8];
            #pragma unroll
            for (int j = 0; j < 8; ++j) accj[j] = 0.0;
            #pragma unroll
            for (int u = 0; u < 16; ++u) {
                int k = sL + 8 * u;
                double s = sStateD[rLN][k];
                float4 w0 = *(const float4*)&sWo[k][0];
                float4 w1 = *(const float4*)&sWo[k][4];
                accj[0] = fma(s, (double)w0.x, accj[0]);
                accj[1] = fma(s, (double)w0.y, accj[1]);
                accj[2] = fma(s, (double)w0.z, accj[2]);
                accj[3] = fma(s, (double)w0.w, accj[3]);
                accj[4] = fma(s, (double)w1.x, accj[4]);
                accj[5] = fma(s, (double)w1.y, accj[5]);
                accj[6] = fma(s, (double)w1.z, accj[6]);
                accj[7] = fma(s, (double)w1.w, accj[7]);
            }
            #pragma unroll
            for (int j = 0; j < 8; ++j) {
                accj[j] += __shfl_xor(accj[j], 1);
                accj[j] += __shfl_xor(accj[j], 2);
                accj[j] += __shfl_xor(accj[j], 4);
            }
            // register-only select of accj[sL] (cndmask chain, avoids scratch)
            double o = accj[0];
            #pragma unroll
            for (int j = 1; j < 8; ++j) o = (sL == j) ? accj[j] : o;
            out[((rowg + (size_t)rLN) * TT + (size_t)t) * NB + sL] =
                (float)(o + (double)sBo[sL]);
        }
    }
}

extern "C" void kernel_launch(void* const* d_in, const int* in_sizes, int n_in,
                              void* d_out, int out_size, void* d_ws, size_t ws_size,
                              hipStream_t stream) {
    const float* x       = (const float*)d_in[0];
    const float* Wi      = (const float*)d_in[1];
    const float* bi      = (const float*)d_in[2];
    const float* Wo      = (const float*)d_in[3];
    const float* bo      = (const float*)d_in[4];
    const float* g_state = (const float*)d_in[5];
    const float* b_state = (const float*)d_in[6];
    const float* Ws      = (const float*)d_in[7];
    const float* bs      = (const float*)d_in[8];
    const float* gs      = (const float*)d_in[9];
    const float* betas   = (const float*)d_in[10];
    float* out = (float*)d_out;

    const int B = in_sizes[0] / (TT * NB);   // 65536
    dim3 grid(B / BR), block(BDIM);
    hipLaunchKernelGGL(miniphi_kernel, grid, block, 0, stream,
                       x, Wi, bi, Wo, bo, g_state, b_state, Ws, bs, gs, betas, out);
}